// Round 1
// 376.599 us; speedup vs baseline: 1.0278x; 1.0278x over previous
//
#include <hip/hip_runtime.h>

// YOLO-style loss: pred/target (bs, 7, 7, 30) fp32 -> scalar.
// S=7, B=2 boxes (5 ch each), C=20 classes. Memory-bound streaming reduction.
//
// v2: direct-load structure (no LDS staging). Each thread owns one cell and
// loads its 120 contiguous bytes per tensor as 15x float2 (8B-aligned since
// 120 % 8 == 0); class channels are consumed on the fly so only the 10 box
// channels of each tensor stay live. Removes the 60KB LDS tile (occupancy
// was capped at 2 blocks/CU), the load->syncthreads->compute serialization,
// and 1.65M 4-way LDS bank conflicts (stride-30 reads). Per-cell math and
// reduction tree identical to v1 (absmax was 0.0).
// Pass 2: single block reduces per-block partials -> out[0]. Deterministic.
// Fallback (ws too small): zero-init + one atomicAdd per block.

#define CH 30
#define SDIV 7.0f

__device__ __forceinline__ float2 ld2(const float* __restrict__ p, int off) {
    return *reinterpret_cast<const float2*>(p + off);
}

template <bool USE_ATOMIC>
__global__ __launch_bounds__(256) void yolo_loss_pass1(
    const float* __restrict__ pred, const float* __restrict__ tgt,
    float* __restrict__ dst, long long n_cells, float scale)
{
    __shared__ float wsums[4];

    const int tid = threadIdx.x;
    const long long cell = (long long)blockIdx.x * 256 + tid;

    float cell_loss = 0.0f;
    if (cell < n_cells) {
        const float* __restrict__ p = pred + cell * CH;
        const float* __restrict__ t = tgt  + cell * CH;

        // box channels 0..9 of both tensors (stay live in registers)
        const float2 pa = ld2(p, 0), pb = ld2(p, 2), pc = ld2(p, 4),
                     pd = ld2(p, 6), pe = ld2(p, 8);
        const float2 ta = ld2(t, 0), tb = ld2(t, 2), tc = ld2(t, 4),
                     td = ld2(t, 6), te = ld2(t, 8);

        // class loss (channels 10..29) -- consumed as loaded, nothing kept
        float l_class = 0.0f;
        #pragma unroll
        for (int c = 10; c < 30; c += 2) {
            const float2 pv = ld2(p, c);
            const float2 tv = ld2(t, c);
            const float d0 = pv.x - tv.x;
            const float d1 = pv.y - tv.y;
            l_class += d0 * d0 + d1 * d1;
        }

        const float obj   = (tc.x > 0.0f) ? 1.0f : 0.0f;   // t[4]
        const float noobj = 1.0f - obj;

        // no-object confidence loss (conf channels 4 and 9)
        const float d4 = pc.x - tc.x;   // p[4]-t[4]
        const float d9 = pe.y - te.y;   // p[9]-t[9]
        const float l_noobj = d4 * d4 + d9 * d9;

        // target box 0 -> xyxy (matches reference op order)
        const float t_x0 = ta.x / SDIV - 0.5f * tb.x;
        const float t_y0 = ta.y / SDIV - 0.5f * tb.y;
        const float t_x1 = ta.x / SDIV + 0.5f * tb.x;
        const float t_y1 = ta.y / SDIV + 0.5f * tb.y;
        const float area_t = (t_x1 - t_x0) * (t_y1 - t_y0);

        // pred box 0: ch 0..4 = pa.x pa.y pb.x pb.y pc.x
        float iou0;
        {
            const float x0 = pa.x / SDIV - 0.5f * pb.x;
            const float y0 = pa.y / SDIV - 0.5f * pb.y;
            const float x1 = pa.x / SDIV + 0.5f * pb.x;
            const float y1 = pa.y / SDIV + 0.5f * pb.y;
            const float ltx = fmaxf(x0, t_x0);
            const float lty = fmaxf(y0, t_y0);
            const float rbx = fminf(x1, t_x1);
            const float rby = fminf(y1, t_y1);
            const float w = fmaxf(rbx - ltx, 0.0f);
            const float h = fmaxf(rby - lty, 0.0f);
            const float inter  = w * h;
            const float area_p = (x1 - x0) * (y1 - y0);
            const float uni = fmaxf(area_p + area_t - inter, 1e-10f);
            iou0 = inter / uni;
        }
        // pred box 1: ch 5..9 = pc.y pd.x pd.y pe.x pe.y
        float iou1;
        {
            const float x0 = pc.y / SDIV - 0.5f * pd.y;
            const float y0 = pd.x / SDIV - 0.5f * pe.x;
            const float x1 = pc.y / SDIV + 0.5f * pd.y;
            const float y1 = pd.x / SDIV + 0.5f * pe.x;
            const float ltx = fmaxf(x0, t_x0);
            const float lty = fmaxf(y0, t_y0);
            const float rbx = fminf(x1, t_x1);
            const float rby = fminf(y1, t_y1);
            const float w = fmaxf(rbx - ltx, 0.0f);
            const float h = fmaxf(rby - lty, 0.0f);
            const float inter  = w * h;
            const float area_p = (x1 - x0) * (y1 - y0);
            const float uni = fmaxf(area_p + area_t - inter, 1e-10f);
            iou1 = inter / uni;
        }

        // jnp.argmax picks first on ties -> box1 only if strictly greater
        const bool  bsel    = (iou1 > iou0);
        const float max_iou = bsel ? iou1 : iou0;

        // responsible pred box channels
        const float prx = bsel ? pc.y : pa.x;
        const float pry = bsel ? pd.x : pa.y;
        const float prw = bsel ? pd.y : pb.x;
        const float prh = bsel ? pe.x : pb.y;
        const float prc = bsel ? pe.y : pc.x;
        // responsible target box channels
        const float trx = bsel ? tc.y : ta.x;
        const float try_ = bsel ? td.x : ta.y;
        const float trw = bsel ? td.y : tb.x;
        const float trh = bsel ? te.x : tb.y;

        const float dx = prx - trx;
        const float dy = pry - try_;
        const float l_xy = dx * dx + dy * dy;
        const float dw = sqrtf(prw) - sqrtf(trw);
        const float dh = sqrtf(prh) - sqrtf(trh);
        const float l_wh = dw * dw + dh * dh;
        const float dc = prc - max_iou;
        const float l_obj = dc * dc;

        cell_loss = obj * (5.0f * (l_xy + l_wh) + l_obj + l_class)
                  + 0.5f * noobj * l_noobj;
    }

    // ---- reduce: wave64 shuffle -> per-wave LDS -> per-block result ----
    float v = cell_loss;
    #pragma unroll
    for (int off = 32; off > 0; off >>= 1)
        v += __shfl_down(v, off, 64);

    const int wave = tid >> 6;
    const int lane = tid & 63;
    if (lane == 0) wsums[wave] = v;
    __syncthreads();
    if (tid == 0) {
        const float s = wsums[0] + wsums[1] + wsums[2] + wsums[3];
        if (USE_ATOMIC) atomicAdd(dst, s * scale);
        else            dst[blockIdx.x] = s;
    }
}

__global__ __launch_bounds__(256) void yolo_loss_pass2(
    const float* __restrict__ partials, float* __restrict__ out,
    int n_partials, float scale)
{
    __shared__ float wsums[4];
    const int tid = threadIdx.x;

    float v = 0.0f;
    for (int i = tid; i < n_partials; i += 256)
        v += partials[i];

    #pragma unroll
    for (int off = 32; off > 0; off >>= 1)
        v += __shfl_down(v, off, 64);

    const int wave = tid >> 6;
    const int lane = tid & 63;
    if (lane == 0) wsums[wave] = v;
    __syncthreads();
    if (tid == 0)
        out[0] = (wsums[0] + wsums[1] + wsums[2] + wsums[3]) * scale;
}

__global__ __launch_bounds__(64) void zero_out_kernel(float* out) {
    if (threadIdx.x == 0) out[0] = 0.0f;
}

extern "C" void kernel_launch(void* const* d_in, const int* in_sizes, int n_in,
                              void* d_out, int out_size, void* d_ws, size_t ws_size,
                              hipStream_t stream) {
    const float* pred = (const float*)d_in[0];
    const float* tgt  = (const float*)d_in[1];
    float* out = (float*)d_out;
    float* partials = (float*)d_ws;

    const long long total   = (long long)in_sizes[0];
    const long long n_cells = total / CH;          // bs*S*S
    const long long bs      = n_cells / 49;        // S*S = 49
    const float scale = 1.0f / (float)bs;

    const int grid = (int)((n_cells + 255) / 256);

    if (ws_size >= (size_t)grid * sizeof(float)) {
        // deterministic two-pass path
        yolo_loss_pass1<false><<<grid, 256, 0, stream>>>(pred, tgt, partials,
                                                         n_cells, scale);
        yolo_loss_pass2<<<1, 256, 0, stream>>>(partials, out, grid, scale);
    } else {
        // fallback: zero-init + one atomic per block
        zero_out_kernel<<<1, 64, 0, stream>>>(out);
        yolo_loss_pass1<true><<<grid, 256, 0, stream>>>(pred, tgt, out,
                                                        n_cells, scale);
    }
}